// Round 19
// baseline (116.074 us; speedup 1.0000x reference)
//
#include <hip/hip_runtime.h>
#include <cstdint>
#include <cstddef>

// ---------- types ----------
typedef __bf16 bf16;
typedef __attribute__((ext_vector_type(8))) __bf16 bf16x8;
typedef __attribute__((ext_vector_type(4))) float f32x4;
typedef __attribute__((ext_vector_type(16))) float f32x16;
typedef __attribute__((ext_vector_type(4))) short short4v;

#define MFMA16(a, b, c) __builtin_amdgcn_mfma_f32_16x16x32_bf16((a), (b), (c), 0, 0, 0)
#define MFMA32(a, b, c) __builtin_amdgcn_mfma_f32_32x32x16_bf16((a), (b), (c), 0, 0, 0)

// Problem constants (B=2, S=2048, HIDDEN=1024, H=16, D=64)
static constexpr int BB   = 2;
static constexpr int SS   = 2048;
static constexpr int HID  = 1024;
static constexpr int NH   = 16;
static constexpr int HD   = 64;
static constexpr int MROW = BB * SS;     // 4096
static constexpr int NQKV = 3 * HID;     // 3072
static constexpr float LOG2E = 1.4426950408889634f;
static constexpr float MSHIFT = 16.0f;   // static softmax shift (log2 domain)

// XOR swizzle on 16B slots
__device__ __forceinline__ int SW(int r) { return ((r ^ (r >> 3)) & 7) << 4; }

__device__ __forceinline__ uint32_t pack_bf16(float a, float b) {
    union { bf16 h[2]; uint32_t u; } x;
    x.h[0] = (bf16)a; x.h[1] = (bf16)b;
    return x.u;
}

__device__ __forceinline__ float exp2i(float x) {
    float r; asm("v_exp_f32 %0, %1" : "=v"(r) : "v"(x)); return r;
}

// v_permlane32_swap_b32: a' = [a.lo | b.lo], b' = [a.hi | b.hi]
__device__ __forceinline__ void plswap(uint32_t& a, uint32_t& b) {
    asm("v_permlane32_swap_b32 %0, %1" : "+v"(a), "+v"(b));
}

// async global->LDS, 16B per lane
__device__ __forceinline__ void gload16(const void* g, void* l) {
    __builtin_amdgcn_global_load_lds(
        (const __attribute__((address_space(1))) void*)g,
        (__attribute__((address_space(3))) void*)l, 16, 0, 0);
}

// ---------- kernel 1: fp32 -> bf16 convert (+ fused mask precompute) ----------
__global__ __launch_bounds__(256) void cvt_hidden(const float* __restrict__ in,
                                                  bf16* __restrict__ out,
                                                  const float* __restrict__ msk,
                                                  float* __restrict__ mk2) {
    const int blk = blockIdx.x;
    if (blk >= 2048) {                       // 16 tail blocks: mask * log2e - 16
        const int i = (blk - 2048) * 256 + threadIdx.x;   // 0..4095
        mk2[i] = msk[i] * LOG2E - MSHIFT;
        return;
    }
    const int i = (blk * 256 + threadIdx.x) * 8;
    float4 f0 = *(const float4*)&in[i];
    float4 f1 = *(const float4*)&in[i + 4];
    bf16x8 o;
    o[0] = (bf16)f0.x; o[1] = (bf16)f0.y; o[2] = (bf16)f0.z; o[3] = (bf16)f0.w;
    o[4] = (bf16)f1.x; o[5] = (bf16)f1.y; o[6] = (bf16)f1.z; o[7] = (bf16)f1.w;
    *(bf16x8*)&out[i] = o;
}

// ---------- kernel 2: transpose-convert W -> Wt [n][k] bf16 ----------
__global__ __launch_bounds__(256) void wtrans(const float* __restrict__ Wq,
                                              const float* __restrict__ Wk,
                                              const float* __restrict__ Wv,
                                              bf16* __restrict__ Wt) {
    __shared__ float tile[32][33];
    const float* W = (blockIdx.z == 0) ? Wq : (blockIdx.z == 1) ? Wk : Wv;
    bf16* O = Wt + (size_t)blockIdx.z * HID * HID;
    const int x  = blockIdx.x * 32 + threadIdx.x;
    const int y0 = blockIdx.y * 32;
#pragma unroll
    for (int i = threadIdx.y; i < 32; i += 8)
        tile[i][threadIdx.x] = W[(size_t)(y0 + i) * HID + x];
    __syncthreads();
    const int k = y0 + threadIdx.x;
#pragma unroll
    for (int i = threadIdx.y; i < 32; i += 8)
        O[(size_t)(blockIdx.x * 32 + i) * HID + k] = (bf16)tile[threadIdx.x][i];
}

// ---------- kernel 3: QKV GEMM — triple-buffer, counted vmcnt (T4) ----------
// R18 attn's hazard-audited schedule transplanted: compute(buf[t%3]) ;
// stage(t+2 -> buf[(t+2)%3]) ; vmcnt(4) [retires t+1] ; s_barrier.
// No full vmcnt(0) drain per K-step (the documented ~20% stall of the
// 2-barrier m97 structure). Q,K out [B,H,S,D]; V out [BH][D][S].
__global__ __launch_bounds__(256) void qkv_gemm(
    const bf16* __restrict__ A, const bf16* __restrict__ Bt,
    const float* __restrict__ bq, const float* __restrict__ bk,
    const float* __restrict__ bv,
    bf16* __restrict__ Qo, bf16* __restrict__ Ko, bf16* __restrict__ Vo) {
    __shared__ __align__(16) bf16 As0[128 * 32];
    __shared__ __align__(16) bf16 As1[128 * 32];
    __shared__ __align__(16) bf16 As2[128 * 32];
    __shared__ __align__(16) bf16 Bs0[128 * 32];
    __shared__ __align__(16) bf16 Bs1[128 * 32];
    __shared__ __align__(16) bf16 Bs2[128 * 32];
    const int t = threadIdx.x, l = t & 63;
    const int l15 = l & 15, l4 = l >> 4;
    const int w = t >> 6;
    const int wm = w >> 1, wn = w & 1;

    const int bid = blockIdx.x;
    const int nid = (bid & 7) * 96 + (bid >> 3);   // bijective: 768 = 8*96
    const int m0 = (nid & 31) * 128;
    const int n0 = (nid >> 5) * 128;

    f32x4 acc[4][4] = {};

    auto stage = [&](int kt, bf16* Asd, bf16* Bsd) {
        const int k0 = kt * 32;
#pragma unroll
        for (int cc = 0; cc < 2; ++cc) {
            const int c = t + cc * 256;
            const int row = c >> 2, col = (c & 3) * 8;
            gload16(&A[(size_t)(m0 + row) * HID + k0 + col], (char*)Asd + c * 16);
            gload16(&Bt[(size_t)(n0 + row) * HID + k0 + col], (char*)Bsd + c * 16);
        }
    };
    auto selA = [&](int i) -> bf16* { return (i == 0) ? As0 : (i == 1) ? As1 : As2; };
    auto selB = [&](int i) -> bf16* { return (i == 0) ? Bs0 : (i == 1) ? Bs1 : Bs2; };

    // prologue: stage tiles 0,1 (8 DMA); retire tile0's 4
    stage(0, As0, Bs0);
    stage(1, As1, Bs1);
    asm volatile("s_waitcnt vmcnt(4)" ::: "memory");
    __builtin_amdgcn_sched_barrier(0);
    __builtin_amdgcn_s_barrier();

    int cur = 0, nx2 = 2;
#pragma unroll 1
    for (int kt = 0; kt < 32; ++kt) {
        bf16* As = selA(cur);
        bf16* Bs = selB(cur);

        bf16x8 af[4], bf_[4];
#pragma unroll
        for (int mi = 0; mi < 4; ++mi) {
            const int r = wm * 64 + mi * 16 + l15;
            af[mi] = *(const bf16x8*)((const char*)As + r * 64 + l4 * 16);
        }
#pragma unroll
        for (int ni = 0; ni < 4; ++ni) {
            const int r = wn * 64 + ni * 16 + l15;
            bf_[ni] = *(const bf16x8*)((const char*)Bs + r * 64 + l4 * 16);
        }
        __builtin_amdgcn_s_setprio(1);
#pragma unroll
        for (int mi = 0; mi < 4; ++mi)
#pragma unroll
            for (int ni = 0; ni < 4; ++ni)
                acc[mi][ni] = MFMA16(af[mi], bf_[ni], acc[mi][ni]);
        __builtin_amdgcn_s_setprio(0);

        // stage t+2 into buf[(t+2)%3] (last read at t-1, barrier-ordered)
        {
            const int nx = (kt + 2 < 32) ? kt + 2 : 31;   // clamped tail
            stage(nx, selA(nx2), selB(nx2));
        }
        asm volatile("s_waitcnt vmcnt(4)" ::: "memory");  // t+1's DMA retired
        __builtin_amdgcn_sched_barrier(0);
        __builtin_amdgcn_s_barrier();        // publish t+1
        cur = (cur == 2) ? 0 : cur + 1;
        nx2 = (nx2 == 2) ? 0 : nx2 + 1;
    }

#pragma unroll
    for (int mi = 0; mi < 4; ++mi) {
#pragma unroll
        for (int ni = 0; ni < 4; ++ni) {
            const int ng = n0 + wn * 64 + ni * 16 + l15;
            const int qkv = ng >> 10;       // uniform across 16-lane group
            const int nn = ng & 1023;
            const int hh = nn >> 6, dd = nn & 63;
            const int mg = m0 + wm * 64 + mi * 16 + l4 * 4;
            const int bb = mg >> 11, ss = mg & 2047;
            if (qkv == 2) {
                const float bias = bv[nn];
                union { bf16 h[4]; short4v s4; } pk_;
#pragma unroll
                for (int j = 0; j < 4; ++j)
                    pk_.h[j] = (bf16)(acc[mi][ni][j] + bias);
                bf16* dst = Vo + ((size_t)(bb * NH + hh) * HD + dd) * SS + ss;
                *(short4v*)dst = pk_.s4;    // ss % 4 == 0 -> 8B aligned
            } else {
                const float* bp = (qkv == 0) ? bq : bk;
                bf16* op = (qkv == 0) ? Qo : Ko;
                const float bias = bp[nn];
                const float scl = (qkv == 0) ? 0.125f * LOG2E : 1.0f;
                bf16* dst = op + ((size_t)(bb * NH + hh) * SS + ss) * HD + dd;
#pragma unroll
                for (int j = 0; j < 4; ++j)
                    dst[(size_t)j * HD] = (bf16)((acc[mi][ni][j] + bias) * scl);
            }
        }
    }
}

// ---------- kernel 4: flash attention v18 — triple-buffer, 1 barrier/tile ----
// (unchanged from R18)
__global__ __launch_bounds__(256) void attn_fwd(
    const bf16* __restrict__ Q, const bf16* __restrict__ K,
    const bf16* __restrict__ Vt_g, const float* __restrict__ mkl,
    float* __restrict__ out) {
    __shared__ __align__(16) char Ks0[64 * 128];
    __shared__ __align__(16) char Ks1[64 * 128];
    __shared__ __align__(16) char Ks2[64 * 128];
    __shared__ __align__(16) char Vt0[64 * 128];
    __shared__ __align__(16) char Vt1[64 * 128];
    __shared__ __align__(16) char Vt2[64 * 128];
    __shared__ __align__(16) float Mk[SS];          // mask' row in LDS (8 KB)

    const int t = threadIdx.x, l = t & 63, w = t >> 6;
    const int l31 = l & 31, h = l >> 5;

    const int bid = blockIdx.x;
    const int nid = (bid & 7) * 64 + (bid >> 3);   // 512 = 8*64 bijective
    const int bh = nid >> 4, qb = nid & 15;
    const int b = bh >> 4, hh = bh & 15;
    const int q0 = qb * 128 + w * 32;

    const bf16* Qp  = Q + (size_t)bh * SS * HD;
    const bf16* Kp  = K + (size_t)bh * SS * HD;
    const bf16* Vpt = Vt_g + (size_t)bh * HD * SS;   // [D][S]
    const float* mkp = mkl + b * SS;

    // Q frags (B-operand): lane q = l31, d = c*16 + h*8 + e
    bf16x8 qf[4];
#pragma unroll
    for (int c = 0; c < 4; ++c)
        qf[c] = *(const bf16x8*)&Qp[(size_t)(q0 + l31) * HD + c * 16 + h * 8];

    float lrun = 0.f;
    f32x16 o0 = {}, o1 = {};   // O^T: rows d / d+32, col q = l31

    // ---- staging helpers (4 DMA per tile per thread-block) ----
    auto stageK = [&](int tile, char* dst) {
        const int key0 = tile * 64;
#pragma unroll
        for (int cc = 0; cc < 2; ++cc) {
            const int c = t + cc * 256;
            const int row = c >> 3;                  // key
            const int csw = (c & 7) ^ ((row ^ (row >> 3)) & 7);
            gload16(&Kp[(size_t)(key0 + row) * HD + csw * 8], dst + c * 16);
        }
    };
    auto stageVt = [&](int tile, char* dst) {
        const int key0 = tile * 64;
#pragma unroll
        for (int cc = 0; cc < 2; ++cc) {
            const int c = t + cc * 256;
            const int row = c >> 3;                  // d
            const int csw = (c & 7) ^ ((row ^ (row >> 3)) & 7);
            gload16(&Vpt[(size_t)row * SS + key0 + csw * 8], dst + c * 16);
        }
    };
    auto selK = [&](int i) -> char* { return (i == 0) ? Ks0 : (i == 1) ? Ks1 : Ks2; };
    auto selV = [&](int i) -> char* { return (i == 0) ? Vt0 : (i == 1) ? Vt1 : Vt2; };

    // ---- prologue: tile0 (4) -> mask (2) -> tile1 (4); retire oldest 6 ----
    stageK(0, Ks0);
    stageVt(0, Vt0);
    gload16(&mkp[t * 4], (char*)Mk + t * 16);               // first 4 KB
    gload16(&mkp[1024 + t * 4], (char*)Mk + 4096 + t * 16); // second 4 KB
    stageK(1, Ks1);
    stageVt(1, Vt1);
    asm volatile("s_waitcnt vmcnt(4)" ::: "memory"); // tile0 + mask landed
    __builtin_amdgcn_sched_barrier(0);
    __builtin_amdgcn_s_barrier();

    constexpr int NT = SS / 64;   // 32
    int cur = 0, nx2 = 2;         // cur = kt%3, nx2 = (kt+2)%3
#pragma unroll 1
    for (int kt = 0; kt < NT; ++kt) {
        char* Ks = selK(cur);
        char* Vt = selV(cur);
        const int key0 = kt * 64;

        // ---- QK^T both groups; C-operand = mask' (from LDS, broadcast) ----
        f32x16 s0, s1;
#pragma unroll
        for (int rq = 0; rq < 4; ++rq) {
            const f32x4 m0v = *(const f32x4*)&Mk[key0 + rq * 8 + 4 * h];
            const f32x4 m1v = *(const f32x4*)&Mk[key0 + 32 + rq * 8 + 4 * h];
#pragma unroll
            for (int j = 0; j < 4; ++j) {
                s0[rq * 4 + j] = m0v[j];
                s1[rq * 4 + j] = m1v[j];
            }
        }
        __builtin_amdgcn_s_setprio(1);
#pragma unroll
        for (int c = 0; c < 4; ++c) {
            const int r0 = l31;
            bf16x8 kf0 = *(const bf16x8*)(Ks + r0 * 128 +
                                          ((c * 32 + h * 16) ^ SW(r0)));
            s0 = MFMA32(kf0, qf[c], s0);
        }
#pragma unroll
        for (int c = 0; c < 4; ++c) {
            const int r1 = 32 + l31;
            bf16x8 kf1 = *(const bf16x8*)(Ks + r1 * 128 +
                                          ((c * 32 + h * 16) ^ SW(r1)));
            s1 = MFMA32(kf1, qf[c], s1);
        }
        __builtin_amdgcn_s_setprio(0);

        // ---- softmax + PV per group (static shift; p = 2^s) ----
#pragma unroll
        for (int g = 0; g < 2; ++g) {
            f32x16& st = g ? s1 : s0;
            float ps = 0.f;
#pragma unroll
            for (int r = 0; r < 16; ++r) {
                const float p = exp2i(st[r]);
                st[r] = p;
                ps += p;
            }
            lrun += ps;
#pragma unroll
            for (int cc = 0; cc < 2; ++cc) {
                uint32_t wA = pack_bf16(st[8 * cc + 0], st[8 * cc + 1]);
                uint32_t wB = pack_bf16(st[8 * cc + 2], st[8 * cc + 3]);
                uint32_t wC = pack_bf16(st[8 * cc + 4], st[8 * cc + 5]);
                uint32_t wD = pack_bf16(st[8 * cc + 6], st[8 * cc + 7]);
                plswap(wA, wC);
                plswap(wB, wD);
                union { uint32_t u[4]; bf16x8 v; } pb;
                pb.u[0] = wA; pb.u[1] = wB; pb.u[2] = wC; pb.u[3] = wD;
                const int colb = g * 64 + cc * 32 + h * 16;
                __builtin_amdgcn_s_setprio(1);
                {
                    bf16x8 vf0 = *(const bf16x8*)(Vt + l31 * 128 +
                                                  (colb ^ SW(l31)));
                    o0 = MFMA32(vf0, pb.v, o0);
                    const int r1 = 32 + l31;
                    bf16x8 vf1 = *(const bf16x8*)(Vt + r1 * 128 +
                                                  (colb ^ SW(r1)));
                    o1 = MFMA32(vf1, pb.v, o1);
                }
                __builtin_amdgcn_s_setprio(0);
            }
        }

        // ---- stage t+2 into buf[(t+2)%3]; ONE barrier publishes t+1 ----
        {
            const int nx = (kt + 2 < NT) ? kt + 2 : NT - 1;   // clamped
            stageK(nx, selK(nx2));
            stageVt(nx, selV(nx2));
        }
        asm volatile("s_waitcnt vmcnt(4)" ::: "memory");  // t+1's DMA retired
        __builtin_amdgcn_sched_barrier(0);
        __builtin_amdgcn_s_barrier();        // t+1 visible block-wide
        cur = (cur == 2) ? 0 : cur + 1;
        nx2 = (nx2 == 2) ? 0 : nx2 + 1;
    }

    // ---- epilogue: drain tail DMA, normalize, LDS bounce, coalesced store ----
    __syncthreads();
    lrun += __shfl_xor(lrun, 32);
    const float inv = 1.0f / lrun;
    char* myB = (w == 0) ? Ks0 : (w == 1) ? Ks1 : (w == 2) ? Vt0 : Vt1;
#pragma unroll
    for (int r4 = 0; r4 < 4; ++r4) {
        f32x4 a, b2;
#pragma unroll
        for (int j = 0; j < 4; ++j) {
            a[j]  = o0[r4 * 4 + j] * inv;
            b2[j] = o1[r4 * 4 + j] * inv;
        }
        const int s0_ = 2 * r4 + h;
        const int s1_ = 8 + 2 * r4 + h;
        *(f32x4*)(myB + l31 * 256 + ((s0_ ^ (l31 & 15)) * 16)) = a;
        *(f32x4*)(myB + l31 * 256 + ((s1_ ^ (l31 & 15)) * 16)) = b2;
    }
    const int qr = l >> 1, halfd = l & 1;
    float* op = &out[((size_t)(b * SS) + q0 + qr) * HID + hh * HD + halfd * 32];
#pragma unroll
    for (int s = 0; s < 8; ++s) {
        const int slot = halfd * 8 + s;
        f32x4 v = *(const f32x4*)(myB + qr * 256 + ((slot ^ (qr & 15)) * 16));
        *(f32x4*)(op + s * 4) = v;
    }
}

// ---------- launch ----------
extern "C" void kernel_launch(void* const* d_in, const int* in_sizes, int n_in,
                              void* d_out, int out_size, void* d_ws, size_t ws_size,
                              hipStream_t stream) {
    (void)in_sizes; (void)n_in; (void)out_size; (void)ws_size;
    const float* hs  = (const float*)d_in[0];
    const float* msk = (const float*)d_in[1];
    const float* Wq  = (const float*)d_in[2];
    const float* bq  = (const float*)d_in[3];
    const float* Wk  = (const float*)d_in[4];
    const float* bk  = (const float*)d_in[5];
    const float* Wv  = (const float*)d_in[6];
    const float* bv  = (const float*)d_in[7];
    float* out = (float*)d_out;
    char* ws = (char*)d_ws;
    const size_t MB = 1 << 20;

    bf16* Qb  = (bf16*)ws;                    // 0..8MB   [B,H,S,D]
    bf16* Kb  = (bf16*)(ws + 8 * MB);         // 8..16    [B,H,S,D]
    bf16* Vb  = (bf16*)(ws + 16 * MB);        // 16..24   [BH][D][S] (transposed)
    float* mk2 = (float*)(ws + 24 * MB);      // 24MB + 16KB
    bf16* Xb  = (bf16*)(ws + 25 * MB);        // 25..33
    bf16* Wt  = (bf16*)(ws + 33 * MB);        // 33..39

    cvt_hidden<<<dim3(2048 + 16), dim3(256), 0, stream>>>(hs, Xb, msk, mk2);
    wtrans<<<dim3(32, 32, 3), dim3(32, 8), 0, stream>>>(Wq, Wk, Wv, Wt);
    qkv_gemm<<<dim3(768), dim3(256), 0, stream>>>(
        Xb, Wt, bq, bk, bv, Qb, Kb, Vb);
    attn_fwd<<<dim3(512), dim3(256), 0, stream>>>(Qb, Kb, Vb, mk2, out);
}

// Round 20
// 106.999 us; speedup vs baseline: 1.0848x; 1.0848x over previous
//
#include <hip/hip_runtime.h>
#include <cstdint>
#include <cstddef>

// ---------- types ----------
typedef __bf16 bf16;
typedef __attribute__((ext_vector_type(8))) __bf16 bf16x8;
typedef __attribute__((ext_vector_type(4))) float f32x4;
typedef __attribute__((ext_vector_type(16))) float f32x16;
typedef __attribute__((ext_vector_type(4))) short short4v;

#define MFMA16(a, b, c) __builtin_amdgcn_mfma_f32_16x16x32_bf16((a), (b), (c), 0, 0, 0)
#define MFMA32(a, b, c) __builtin_amdgcn_mfma_f32_32x32x16_bf16((a), (b), (c), 0, 0, 0)

// Problem constants (B=2, S=2048, HIDDEN=1024, H=16, D=64)
static constexpr int BB   = 2;
static constexpr int SS   = 2048;
static constexpr int HID  = 1024;
static constexpr int NH   = 16;
static constexpr int HD   = 64;
static constexpr int MROW = BB * SS;     // 4096
static constexpr int NQKV = 3 * HID;     // 3072
static constexpr float LOG2E = 1.4426950408889634f;
static constexpr float MSHIFT = 16.0f;   // static softmax shift (log2 domain)

// XOR swizzle on 16B slots
__device__ __forceinline__ int SW(int r) { return ((r ^ (r >> 3)) & 7) << 4; }

__device__ __forceinline__ uint32_t pack_bf16(float a, float b) {
    union { bf16 h[2]; uint32_t u; } x;
    x.h[0] = (bf16)a; x.h[1] = (bf16)b;
    return x.u;
}

__device__ __forceinline__ float exp2i(float x) {
    float r; asm("v_exp_f32 %0, %1" : "=v"(r) : "v"(x)); return r;
}

// v_permlane32_swap_b32: a' = [a.lo | b.lo], b' = [a.hi | b.hi]
__device__ __forceinline__ void plswap(uint32_t& a, uint32_t& b) {
    asm("v_permlane32_swap_b32 %0, %1" : "+v"(a), "+v"(b));
}

// async global->LDS, 16B per lane
__device__ __forceinline__ void gload16(const void* g, void* l) {
    __builtin_amdgcn_global_load_lds(
        (const __attribute__((address_space(1))) void*)g,
        (__attribute__((address_space(3))) void*)l, 16, 0, 0);
}

// ---------- kernel 1: fused prep — cvt_hidden + maskcvt + wtrans ----------
// grid = 2048 (cvt) + 16 (mask) + 3072 (wtrans) blocks, 256 threads.
// One launch instead of three; HBM streams overlap.
__global__ __launch_bounds__(256) void prep(const float* __restrict__ in,
                                            bf16* __restrict__ out,
                                            const float* __restrict__ msk,
                                            float* __restrict__ mk2,
                                            const float* __restrict__ Wq,
                                            const float* __restrict__ Wk,
                                            const float* __restrict__ Wv,
                                            bf16* __restrict__ Wt) {
    const int blk = blockIdx.x;
    if (blk < 2048) {                        // hidden f32 -> bf16
        const int i = (blk * 256 + threadIdx.x) * 8;
        float4 f0 = *(const float4*)&in[i];
        float4 f1 = *(const float4*)&in[i + 4];
        bf16x8 o;
        o[0] = (bf16)f0.x; o[1] = (bf16)f0.y; o[2] = (bf16)f0.z; o[3] = (bf16)f0.w;
        o[4] = (bf16)f1.x; o[5] = (bf16)f1.y; o[6] = (bf16)f1.z; o[7] = (bf16)f1.w;
        *(bf16x8*)&out[i] = o;
        return;
    }
    if (blk < 2064) {                        // mask * log2e - 16
        const int i = (blk - 2048) * 256 + threadIdx.x;   // 0..4095
        mk2[i] = msk[i] * LOG2E - MSHIFT;
        return;
    }
    // wtrans: block id -> (z, by, bx); threads (32 x 8) from t
    __shared__ float tile[32][33];
    const int wb = blk - 2064;               // 0..3071
    const int z = wb >> 10, rem = wb & 1023;
    const int by = rem >> 5, bx = rem & 31;
    const int tx = threadIdx.x & 31, ty = threadIdx.x >> 5;
    const float* W = (z == 0) ? Wq : (z == 1) ? Wk : Wv;
    bf16* O = Wt + (size_t)z * HID * HID;
    const int x  = bx * 32 + tx;             // n
    const int y0 = by * 32;                  // k
#pragma unroll
    for (int i = ty; i < 32; i += 8)
        tile[i][tx] = W[(size_t)(y0 + i) * HID + x];
    __syncthreads();
    const int k = y0 + tx;
#pragma unroll
    for (int i = ty; i < 32; i += 8)
        O[(size_t)(bx * 32 + i) * HID + k] = (bf16)tile[tx][i];
}

// ---------- kernel 3: QKV GEMM (R18 winner: XCD remap + 2-buf 1-barrier) ----
__global__ __launch_bounds__(256) void qkv_gemm(
    const bf16* __restrict__ A, const bf16* __restrict__ Bt,
    const float* __restrict__ bq, const float* __restrict__ bk,
    const float* __restrict__ bv,
    bf16* __restrict__ Qo, bf16* __restrict__ Ko, bf16* __restrict__ Vo) {
    __shared__ __align__(16) bf16 As0[128 * 32];
    __shared__ __align__(16) bf16 As1[128 * 32];
    __shared__ __align__(16) bf16 Bs0[128 * 32];
    __shared__ __align__(16) bf16 Bs1[128 * 32];
    const int t = threadIdx.x, l = t & 63;
    const int l15 = l & 15, l4 = l >> 4;
    const int w = t >> 6;
    const int wm = w >> 1, wn = w & 1;

    const int bid = blockIdx.x;
    const int nid = (bid & 7) * 96 + (bid >> 3);   // bijective: 768 = 8*96
    const int m0 = (nid & 31) * 128;
    const int n0 = (nid >> 5) * 128;

    f32x4 acc[4][4] = {};

    auto stage = [&](int kt, bf16* Asd, bf16* Bsd) {
        const int k0 = kt * 32;
#pragma unroll
        for (int cc = 0; cc < 2; ++cc) {
            const int c = t + cc * 256;
            const int row = c >> 2, col = (c & 3) * 8;
            gload16(&A[(size_t)(m0 + row) * HID + k0 + col], (char*)Asd + c * 16);
            gload16(&Bt[(size_t)(n0 + row) * HID + k0 + col], (char*)Bsd + c * 16);
        }
    };

    stage(0, As0, Bs0);
    __syncthreads();

#pragma unroll 1
    for (int kt = 0; kt < 32; ++kt) {
        bf16* As = (kt & 1) ? As1 : As0;
        bf16* Bs = (kt & 1) ? Bs1 : Bs0;
        if (kt < 31) stage(kt + 1, (kt & 1) ? As0 : As1, (kt & 1) ? Bs0 : Bs1);

        bf16x8 af[4], bf_[4];
#pragma unroll
        for (int mi = 0; mi < 4; ++mi) {
            const int r = wm * 64 + mi * 16 + l15;
            af[mi] = *(const bf16x8*)((const char*)As + r * 64 + l4 * 16);
        }
#pragma unroll
        for (int ni = 0; ni < 4; ++ni) {
            const int r = wn * 64 + ni * 16 + l15;
            bf_[ni] = *(const bf16x8*)((const char*)Bs + r * 64 + l4 * 16);
        }
        __builtin_amdgcn_s_setprio(1);
#pragma unroll
        for (int mi = 0; mi < 4; ++mi)
#pragma unroll
            for (int ni = 0; ni < 4; ++ni)
                acc[mi][ni] = MFMA16(af[mi], bf_[ni], acc[mi][ni]);
        __builtin_amdgcn_s_setprio(0);
        __syncthreads();   // single barrier: drains next-tile DMA, fences reads
    }

#pragma unroll
    for (int mi = 0; mi < 4; ++mi) {
#pragma unroll
        for (int ni = 0; ni < 4; ++ni) {
            const int ng = n0 + wn * 64 + ni * 16 + l15;
            const int qkv = ng >> 10;       // uniform across 16-lane group
            const int nn = ng & 1023;
            const int hh = nn >> 6, dd = nn & 63;
            const int mg = m0 + wm * 64 + mi * 16 + l4 * 4;
            const int bb = mg >> 11, ss = mg & 2047;
            if (qkv == 2) {
                const float bias = bv[nn];
                union { bf16 h[4]; short4v s4; } pk_;
#pragma unroll
                for (int j = 0; j < 4; ++j)
                    pk_.h[j] = (bf16)(acc[mi][ni][j] + bias);
                bf16* dst = Vo + ((size_t)(bb * NH + hh) * HD + dd) * SS + ss;
                *(short4v*)dst = pk_.s4;    // ss % 4 == 0 -> 8B aligned
            } else {
                const float* bp = (qkv == 0) ? bq : bk;
                bf16* op = (qkv == 0) ? Qo : Ko;
                const float bias = bp[nn];
                const float scl = (qkv == 0) ? 0.125f * LOG2E : 1.0f;
                bf16* dst = op + ((size_t)(bb * NH + hh) * SS + ss) * HD + dd;
#pragma unroll
                for (int j = 0; j < 4; ++j)
                    dst[(size_t)j * HD] = (bf16)((acc[mi][ni][j] + bias) * scl);
            }
        }
    }
}

// ---------- kernel 4: flash attention v18 — triple-buffer, 1 barrier/tile ----
// (unchanged from R18, the best measured attn)
__global__ __launch_bounds__(256) void attn_fwd(
    const bf16* __restrict__ Q, const bf16* __restrict__ K,
    const bf16* __restrict__ Vt_g, const float* __restrict__ mkl,
    float* __restrict__ out) {
    __shared__ __align__(16) char Ks0[64 * 128];
    __shared__ __align__(16) char Ks1[64 * 128];
    __shared__ __align__(16) char Ks2[64 * 128];
    __shared__ __align__(16) char Vt0[64 * 128];
    __shared__ __align__(16) char Vt1[64 * 128];
    __shared__ __align__(16) char Vt2[64 * 128];
    __shared__ __align__(16) float Mk[SS];          // mask' row in LDS (8 KB)

    const int t = threadIdx.x, l = t & 63, w = t >> 6;
    const int l31 = l & 31, h = l >> 5;

    const int bid = blockIdx.x;
    const int nid = (bid & 7) * 64 + (bid >> 3);   // 512 = 8*64 bijective
    const int bh = nid >> 4, qb = nid & 15;
    const int b = bh >> 4, hh = bh & 15;
    const int q0 = qb * 128 + w * 32;

    const bf16* Qp  = Q + (size_t)bh * SS * HD;
    const bf16* Kp  = K + (size_t)bh * SS * HD;
    const bf16* Vpt = Vt_g + (size_t)bh * HD * SS;   // [D][S]
    const float* mkp = mkl + b * SS;

    bf16x8 qf[4];
#pragma unroll
    for (int c = 0; c < 4; ++c)
        qf[c] = *(const bf16x8*)&Qp[(size_t)(q0 + l31) * HD + c * 16 + h * 8];

    float lrun = 0.f;
    f32x16 o0 = {}, o1 = {};   // O^T: rows d / d+32, col q = l31

    auto stageK = [&](int tile, char* dst) {
        const int key0 = tile * 64;
#pragma unroll
        for (int cc = 0; cc < 2; ++cc) {
            const int c = t + cc * 256;
            const int row = c >> 3;                  // key
            const int csw = (c & 7) ^ ((row ^ (row >> 3)) & 7);
            gload16(&Kp[(size_t)(key0 + row) * HD + csw * 8], dst + c * 16);
        }
    };
    auto stageVt = [&](int tile, char* dst) {
        const int key0 = tile * 64;
#pragma unroll
        for (int cc = 0; cc < 2; ++cc) {
            const int c = t + cc * 256;
            const int row = c >> 3;                  // d
            const int csw = (c & 7) ^ ((row ^ (row >> 3)) & 7);
            gload16(&Vpt[(size_t)row * SS + key0 + csw * 8], dst + c * 16);
        }
    };
    auto selK = [&](int i) -> char* { return (i == 0) ? Ks0 : (i == 1) ? Ks1 : Ks2; };
    auto selV = [&](int i) -> char* { return (i == 0) ? Vt0 : (i == 1) ? Vt1 : Vt2; };

    // ---- prologue: tile0 (4) -> mask (2) -> tile1 (4); retire oldest 6 ----
    stageK(0, Ks0);
    stageVt(0, Vt0);
    gload16(&mkp[t * 4], (char*)Mk + t * 16);               // first 4 KB
    gload16(&mkp[1024 + t * 4], (char*)Mk + 4096 + t * 16); // second 4 KB
    stageK(1, Ks1);
    stageVt(1, Vt1);
    asm volatile("s_waitcnt vmcnt(4)" ::: "memory"); // tile0 + mask landed
    __builtin_amdgcn_sched_barrier(0);
    __builtin_amdgcn_s_barrier();

    constexpr int NT = SS / 64;   // 32
    int cur = 0, nx2 = 2;         // cur = kt%3, nx2 = (kt+2)%3
#pragma unroll 1
    for (int kt = 0; kt < NT; ++kt) {
        char* Ks = selK(cur);
        char* Vt = selV(cur);
        const int key0 = kt * 64;

        f32x16 s0, s1;
#pragma unroll
        for (int rq = 0; rq < 4; ++rq) {
            const f32x4 m0v = *(const f32x4*)&Mk[key0 + rq * 8 + 4 * h];
            const f32x4 m1v = *(const f32x4*)&Mk[key0 + 32 + rq * 8 + 4 * h];
#pragma unroll
            for (int j = 0; j < 4; ++j) {
                s0[rq * 4 + j] = m0v[j];
                s1[rq * 4 + j] = m1v[j];
            }
        }
        __builtin_amdgcn_s_setprio(1);
#pragma unroll
        for (int c = 0; c < 4; ++c) {
            const int r0 = l31;
            bf16x8 kf0 = *(const bf16x8*)(Ks + r0 * 128 +
                                          ((c * 32 + h * 16) ^ SW(r0)));
            s0 = MFMA32(kf0, qf[c], s0);
        }
#pragma unroll
        for (int c = 0; c < 4; ++c) {
            const int r1 = 32 + l31;
            bf16x8 kf1 = *(const bf16x8*)(Ks + r1 * 128 +
                                          ((c * 32 + h * 16) ^ SW(r1)));
            s1 = MFMA32(kf1, qf[c], s1);
        }
        __builtin_amdgcn_s_setprio(0);

#pragma unroll
        for (int g = 0; g < 2; ++g) {
            f32x16& st = g ? s1 : s0;
            float ps = 0.f;
#pragma unroll
            for (int r = 0; r < 16; ++r) {
                const float p = exp2i(st[r]);
                st[r] = p;
                ps += p;
            }
            lrun += ps;
#pragma unroll
            for (int cc = 0; cc < 2; ++cc) {
                uint32_t wA = pack_bf16(st[8 * cc + 0], st[8 * cc + 1]);
                uint32_t wB = pack_bf16(st[8 * cc + 2], st[8 * cc + 3]);
                uint32_t wC = pack_bf16(st[8 * cc + 4], st[8 * cc + 5]);
                uint32_t wD = pack_bf16(st[8 * cc + 6], st[8 * cc + 7]);
                plswap(wA, wC);
                plswap(wB, wD);
                union { uint32_t u[4]; bf16x8 v; } pb;
                pb.u[0] = wA; pb.u[1] = wB; pb.u[2] = wC; pb.u[3] = wD;
                const int colb = g * 64 + cc * 32 + h * 16;
                __builtin_amdgcn_s_setprio(1);
                {
                    bf16x8 vf0 = *(const bf16x8*)(Vt + l31 * 128 +
                                                  (colb ^ SW(l31)));
                    o0 = MFMA32(vf0, pb.v, o0);
                    const int r1 = 32 + l31;
                    bf16x8 vf1 = *(const bf16x8*)(Vt + r1 * 128 +
                                                  (colb ^ SW(r1)));
                    o1 = MFMA32(vf1, pb.v, o1);
                }
                __builtin_amdgcn_s_setprio(0);
            }
        }

        // ---- stage t+2 into buf[(t+2)%3]; ONE barrier publishes t+1 ----
        {
            const int nx = (kt + 2 < NT) ? kt + 2 : NT - 1;   // clamped
            stageK(nx, selK(nx2));
            stageVt(nx, selV(nx2));
        }
        asm volatile("s_waitcnt vmcnt(4)" ::: "memory");  // t+1's DMA retired
        __builtin_amdgcn_sched_barrier(0);
        __builtin_amdgcn_s_barrier();        // t+1 visible block-wide
        cur = (cur == 2) ? 0 : cur + 1;
        nx2 = (nx2 == 2) ? 0 : nx2 + 1;
    }

    // ---- epilogue: drain tail DMA, normalize, LDS bounce, coalesced store ----
    __syncthreads();
    lrun += __shfl_xor(lrun, 32);
    const float inv = 1.0f / lrun;
    char* myB = (w == 0) ? Ks0 : (w == 1) ? Ks1 : (w == 2) ? Vt0 : Vt1;
#pragma unroll
    for (int r4 = 0; r4 < 4; ++r4) {
        f32x4 a, b2;
#pragma unroll
        for (int j = 0; j < 4; ++j) {
            a[j]  = o0[r4 * 4 + j] * inv;
            b2[j] = o1[r4 * 4 + j] * inv;
        }
        const int s0_ = 2 * r4 + h;
        const int s1_ = 8 + 2 * r4 + h;
        *(f32x4*)(myB + l31 * 256 + ((s0_ ^ (l31 & 15)) * 16)) = a;
        *(f32x4*)(myB + l31 * 256 + ((s1_ ^ (l31 & 15)) * 16)) = b2;
    }
    const int qr = l >> 1, halfd = l & 1;
    float* op = &out[((size_t)(b * SS) + q0 + qr) * HID + hh * HD + halfd * 32];
#pragma unroll
    for (int s = 0; s < 8; ++s) {
        const int slot = halfd * 8 + s;
        f32x4 v = *(const f32x4*)(myB + qr * 256 + ((slot ^ (qr & 15)) * 16));
        *(f32x4*)(op + s * 4) = v;
    }
}

// ---------- launch ----------
extern "C" void kernel_launch(void* const* d_in, const int* in_sizes, int n_in,
                              void* d_out, int out_size, void* d_ws, size_t ws_size,
                              hipStream_t stream) {
    (void)in_sizes; (void)n_in; (void)out_size; (void)ws_size;
    const float* hs  = (const float*)d_in[0];
    const float* msk = (const float*)d_in[1];
    const float* Wq  = (const float*)d_in[2];
    const float* bq  = (const float*)d_in[3];
    const float* Wk  = (const float*)d_in[4];
    const float* bk  = (const float*)d_in[5];
    const float* Wv  = (const float*)d_in[6];
    const float* bv  = (const float*)d_in[7];
    float* out = (float*)d_out;
    char* ws = (char*)d_ws;
    const size_t MB = 1 << 20;

    bf16* Qb  = (bf16*)ws;                    // 0..8MB   [B,H,S,D]
    bf16* Kb  = (bf16*)(ws + 8 * MB);         // 8..16    [B,H,S,D]
    bf16* Vb  = (bf16*)(ws + 16 * MB);        // 16..24   [BH][D][S] (transposed)
    float* mk2 = (float*)(ws + 24 * MB);      // 24MB + 16KB
    bf16* Xb  = (bf16*)(ws + 25 * MB);        // 25..33
    bf16* Wt  = (bf16*)(ws + 33 * MB);        // 33..39

    prep<<<dim3(2048 + 16 + 3072), dim3(256), 0, stream>>>(
        hs, Xb, msk, mk2, Wq, Wk, Wv, Wt);
    qkv_gemm<<<dim3(768), dim3(256), 0, stream>>>(
        Xb, Wt, bq, bk, bv, Qb, Kb, Vb);
    attn_fwd<<<dim3(512), dim3(256), 0, stream>>>(Qb, Kb, Vb, mk2, out);
}